// Round 13
// baseline (2267.139 us; speedup 1.0000x reference)
//
#include <hip/hip_runtime.h>
#include <hip/hip_bf16.h>
#include <hip/hip_fp16.h>

#define B_TOK 8192
#define ID_DIM 1024
#define LLM_DIM 4096
#define IN_DIM 5120
#define OUT_DIM 2048
#define HID 4096
#define NE 8
#define GH 16
#define NSLOT (2 * B_TOK)

// 256^2 geometry, K-step = 32, A quad-buffered in LDS (64KB), B direct-to-reg
#define NNT1 16      // HID/256
#define NKS1 160     // IN_DIM/32
#define NNT2 8       // OUT_DIM/256
#define NKS2 128     // HID/32
#define MT256 72
#define GRID1B (MT256 * NNT1)   // 1152, %8==0
#define GRID2B (MT256 * NNT2)   // 576,  %8==0

typedef _Float16 f16x8 __attribute__((ext_vector_type(8)));
typedef float f32x4 __attribute__((ext_vector_type(4)));
typedef unsigned short u16;
typedef u16 u16x8 __attribute__((ext_vector_type(8)));

// ---- workspace byte offsets ----
#define OFF_H   (1ull << 20)
#define OFF_X   (OFF_H + (size_t)NSLOT * HID * 2)       // h: 134 MB
#define OFF_P1  (OFF_X + (size_t)B_TOK * IN_DIM * 2)    // Xf16: 84 MB
#define OFF_P2  (OFF_P1 + (size_t)NE * NNT1 * NKS1 * 16384) // packed W1: 335 MB
#define REQ_WS  (OFF_P2 + (size_t)NE * NNT2 * NKS2 * 16384) // packed W2: 134 MB
#define OFF_SLOT OFF_P1   // gemm2 per-slot output aliases dead P1

#define INV_OFF 66560

__device__ __forceinline__ void gll16(void* lds, const void* gsrc) {
  __builtin_amdgcn_global_load_lds(
      (const __attribute__((address_space(1))) unsigned int*)gsrc,
      (__attribute__((address_space(3))) unsigned int*)lds, 16, 0, 0);
}

// ---------------- gate ----------------
__global__ __launch_bounds__(256) void gate_kernel(
    const float* __restrict__ id_emb, const float* __restrict__ llm_emb,
    const float* __restrict__ gW1, const float* __restrict__ gb1,
    const float* __restrict__ gW2, const float* __restrict__ gb2,
    int* __restrict__ wsi, _Float16* __restrict__ xf16) {
  int wave = (blockIdx.x * blockDim.x + threadIdx.x) >> 6;
  int lane = threadIdx.x & 63;
  if (wave >= B_TOK) return;
  int b = wave;
  float acc[GH];
#pragma unroll
  for (int j = 0; j < GH; ++j) acc[j] = 0.f;
  for (int k = lane; k < IN_DIM; k += 64) {
    float x = (k < ID_DIM) ? id_emb[(size_t)b * ID_DIM + k]
                           : llm_emb[(size_t)b * LLM_DIM + (k - ID_DIM)];
    if (xf16) xf16[(size_t)b * IN_DIM + k] = (_Float16)x;
    const float* grow = gW1 + (size_t)k * GH;
#pragma unroll
    for (int j = 0; j < GH; ++j) acc[j] += x * grow[j];
  }
#pragma unroll
  for (int j = 0; j < GH; ++j) {
    for (int off = 32; off > 0; off >>= 1) acc[j] += __shfl_xor(acc[j], off);
  }
  if (lane == 0) {
    float logits[NE];
#pragma unroll
    for (int e = 0; e < NE; ++e) logits[e] = gb2[e];
#pragma unroll
    for (int j = 0; j < GH; ++j) {
      float hg = fmaxf(acc[j] + gb1[j], 0.f);
#pragma unroll
      for (int e = 0; e < NE; ++e) logits[e] += hg * gW2[j * NE + e];
    }
    int i0 = 0; float v0 = logits[0];
#pragma unroll
    for (int e = 1; e < NE; ++e) if (logits[e] > v0) { v0 = logits[e]; i0 = e; }
    int i1 = -1; float v1 = -1e30f;
#pragma unroll
    for (int e = 0; e < NE; ++e) if (e != i0 && logits[e] > v1) { v1 = logits[e]; i1 = e; }
    float ex = expf(v1 - v0);
    float w0 = 1.f / (1.f + ex);
    float w1 = ex / (1.f + ex);
    int* eidx = wsi + 1024;
    float* wsl = (float*)(wsi + 17408);
    eidx[b * 2] = i0; eidx[b * 2 + 1] = i1;
    wsl[b * 2] = w0; wsl[b * 2 + 1] = w1;
    atomicAdd(&wsi[i0], 1);
    atomicAdd(&wsi[i1], 1);
  }
}

// ---------------- schedule: 256-row tiles ----------------
__global__ void schedule_kernel(int* __restrict__ wsi) {
  if (threadIdx.x != 0 || blockIdx.x != 0) return;
  int* counts = wsi; int* cursor = wsi + 8;
  int* te = wsi + 16; int* tm = wsi + 272; int* tc = wsi + 528;
  int off = 0, t = 0;
  for (int e = 0; e < NE; ++e) {
    int c = counts[e];
    cursor[e] = off;
    int nt = (c + 255) >> 8;
    for (int i = 0; i < nt; ++i) {
      te[t] = e; tm[t] = off + i * 256;
      int rem = c - i * 256;
      tc[t] = rem < 256 ? rem : 256;
      ++t;
    }
    off += c;
  }
  for (; t < MT256; ++t) { te[t] = 0; tm[t] = 0; tc[t] = 0; }
}

// ---------------- scatter (+ inverse map) ----------------
__global__ __launch_bounds__(256) void scatter_kernel(int* __restrict__ wsi) {
  int s = blockIdx.x * blockDim.x + threadIdx.x;
  if (s >= NSLOT) return;
  int* cursor = wsi + 8;
  const int* eidx = wsi + 1024;
  const float* wsl = (const float*)(wsi + 17408);
  int* rows = wsi + 33792;
  float* wsorted = (float*)(wsi + 50176);
  int* inv = wsi + INV_OFF;
  int e = eidx[s];
  int pos = atomicAdd(&cursor[e], 1);
  rows[pos] = s;
  wsorted[pos] = wsl[s];
  inv[s] = pos;
}

// ---------------- pack weights: coalesced read -> LDS -> packed blocks ----------------
// Output layout (UNCHANGED): P block 8192 f16 per (e,nt,ks):
//   dst[gn*512 + l*8 + j] = W[k = ks*32 + (l>>4)*8 + j][col = nt*256 + gn*16 + (l&15)]
__global__ __launch_bounds__(256) void pack_w(
    const float* __restrict__ W, _Float16* __restrict__ P,
    int N, int NNT, int NKS) {
  __shared__ _Float16 lds[32 * 264];
  int ks = blockIdx.x, nt = blockIdx.y, e = blockIdx.z;
  const float* src = W + ((size_t)e * NKS * 32 + (size_t)ks * 32) * N + nt * 256;
  _Float16* dst = P + (((size_t)e * NNT + nt) * NKS + ks) * 8192;
  int t = threadIdx.x;
  int r = t >> 3, c0 = (t & 7) * 32;
  const float* srow = src + (size_t)r * N + c0;
#pragma unroll
  for (int i = 0; i < 4; ++i) {
    float4 v0 = *(const float4*)(srow + i * 8);
    float4 v1 = *(const float4*)(srow + i * 8 + 4);
    union { u16x8 u; _Float16 f[8]; } cv;
    cv.f[0] = (_Float16)v0.x; cv.f[1] = (_Float16)v0.y;
    cv.f[2] = (_Float16)v0.z; cv.f[3] = (_Float16)v0.w;
    cv.f[4] = (_Float16)v1.x; cv.f[5] = (_Float16)v1.y;
    cv.f[6] = (_Float16)v1.z; cv.f[7] = (_Float16)v1.w;
    *(u16x8*)&lds[r * 264 + c0 + i * 8] = cv.u;
  }
  __syncthreads();
  int l = t & 63, q = t >> 6;
  int fr = l & 15, kg = l >> 4;
#pragma unroll
  for (int gi = 0; gi < 4; ++gi) {
    int gn = q * 4 + gi;
    union { u16x8 u; _Float16 f[8]; } cv;
#pragma unroll
    for (int j = 0; j < 8; ++j)
      cv.f[j] = lds[(kg * 8 + j) * 264 + gn * 16 + fr];
    *(u16x8*)(dst + gn * 512 + l * 8) = cv.u;
  }
}

// ======================= A-in-LDS / B-in-reg deep GEMM =======================
#define SBAR __builtin_amdgcn_s_barrier()
#define SCHB __builtin_amdgcn_sched_barrier(0)
#define VMW(n) asm volatile("s_waitcnt vmcnt(" #n ")" ::: "memory")

// A stage: LDS dst wave-uniform (HW adds lane*16B); global src per-lane
#define ST_A(Aw, ks_, pa_, gm_) gll16((Aw) + (gm_) * 512, (pa_) + (size_t)(ks_) * 32)
#define STAGE_A(kt)                                                   \
  { _Float16* Aw = smem + ((kt) & 3) * 8192;                          \
    ST_A(Aw, kt, paA, gm_a); ST_A(Aw, kt, paB, gm_b); }

// B direct-to-reg: packed P already in fragment order; 4 x dwordx4 per K-step
#define LOAD_B(Breg, ks_)                                             \
  _Pragma("unroll") for (int n = 0; n < 4; ++n)                       \
      Breg[n] = *(const f16x8*)(pbw + (size_t)(ks_) * 8192 + n * 512);

#define READ_A01(Acp)                                                 \
  _Pragma("unroll") for (int m = 0; m < 4; ++m)                       \
      A0[m] = *(const f16x8*)((Acp) + (wr * 8 + m) * 512 + lane * 8); \
  _Pragma("unroll") for (int m = 0; m < 4; ++m)                       \
      A1[m] = *(const f16x8*)((Acp) + (wr * 8 + 4 + m) * 512 + lane * 8);

#define MFMA_CL(As, Bs, MO)                                           \
  __builtin_amdgcn_s_setprio(1);                                      \
  _Pragma("unroll") for (int m = 0; m < 4; ++m)                       \
      _Pragma("unroll") for (int n = 0; n < 4; ++n)                   \
          acc[(MO) + m][n] = __builtin_amdgcn_mfma_f32_16x16x32_f16(  \
              As[m], Bs[n], acc[(MO) + m][n], 0, 0, 0);               \
  __builtin_amdgcn_s_setprio(0);

// vmcnt ledger (A-only manual; B waits auto-inserted by compiler):
// per iter issues [A-stage: 2 gll16][B-load: 4]; A(k) staged 3 iters back ->
// 16 ops issued after it in steady state. Prologue: 8 / 12. Tail: conservative 8.
#define PIPE_ITER(Bc_, Bn_, k, NKS)                                   \
  { if ((k) >= 2 && (k) < (NKS) - 2) { VMW(16); }                     \
    else if ((k) == 1) { VMW(12); }                                   \
    else { VMW(8); }                                                  \
    SCHB; SBAR;                                                       \
    if ((k) + 3 < (NKS)) STAGE_A((k) + 3);                            \
    if ((k) + 1 < (NKS)) LOAD_B(Bn_, (k) + 1);                        \
    _Float16* Acur = smem + ((k) & 3) * 8192;                         \
    READ_A01(Acur); SCHB;                                             \
    MFMA_CL(A0, Bc_, 0)                                               \
    MFMA_CL(A1, Bc_, 4) }

#define GEMM_PIPE(NKS)                                                \
  f16x8 A0[4], A1[4], Bx[4], By[4];                                   \
  STAGE_A(0) STAGE_A(1) STAGE_A(2)                                    \
  LOAD_B(Bx, 0)                                                       \
  for (int k = 0; k < (NKS); k += 2) {                                \
    PIPE_ITER(Bx, By, k, (NKS))                                       \
    PIPE_ITER(By, Bx, (k + 1), (NKS))                                 \
  }

// ---------------- GEMM1: h = relu(gather(Xf16) @ P1[e] + b1[e]) ----------------
__global__ __launch_bounds__(512, 2) void gemm1_kernel(
    const _Float16* __restrict__ Xf, const _Float16* __restrict__ P1,
    const float* __restrict__ b1, const int* __restrict__ wsi,
    _Float16* __restrict__ hbuf) {
  __shared__ _Float16 smem[32768];  // 64KB: A quad 4x16KB (B stays in regs)
  int d = blockIdx.x;
  int orig = (d & 7) * (GRID1B >> 3) + (d >> 3);
  int tile = orig / NNT1;   // tile-major: XCD chunk shares A m-tiles
  int nt = orig % NNT1;
  int cnt = (wsi + 528)[tile];
  if (cnt == 0) return;
  int e = (wsi + 16)[tile];
  int m0 = (wsi + 272)[tile];
  const int* rows = wsi + 33792;
  int n0 = nt * 256;
  int tid = threadIdx.x, lane = tid & 63, w = tid >> 6;
  int wr = w >> 2, wc = w & 3;
  int fr = lane & 15, kg = lane >> 4;

  int gm_a = wr * 8 + (w & 3);
  int gm_b = gm_a + 4;
  int ra = gm_a * 16 + fr; ra = ra < cnt ? ra : cnt - 1;
  int rb2 = gm_b * 16 + fr; rb2 = rb2 < cnt ? rb2 : cnt - 1;
  const _Float16* paA = Xf + (size_t)(rows[m0 + ra] >> 1) * IN_DIM + kg * 8;
  const _Float16* paB = Xf + (size_t)(rows[m0 + rb2] >> 1) * IN_DIM + kg * 8;
  const _Float16* pbw = P1 + ((size_t)e * NNT1 + nt) * ((size_t)NKS1 * 8192)
                         + (size_t)(wc * 4) * 512 + lane * 8;

  f32x4 acc[8][4];
#pragma unroll
  for (int m = 0; m < 8; ++m)
#pragma unroll
    for (int n = 0; n < 4; ++n) acc[m][n] = (f32x4){0.f, 0.f, 0.f, 0.f};

  GEMM_PIPE(NKS1)

  float bias_n[4];
#pragma unroll
  for (int n = 0; n < 4; ++n) bias_n[n] = b1[e * HID + n0 + wc * 64 + n * 16 + fr];

  // epilogue: relu -> LDS transpose in 4x 64-row quarters -> coalesced 16B h writes
  _Float16* ep = smem;  // [64][264] = 33.8KB of 64KB
#pragma unroll
  for (int q = 0; q < 4; ++q) {
    __syncthreads();
    if (wr == (q >> 1)) {
#pragma unroll
      for (int mi = 0; mi < 4; ++mi) {
        int m = (q & 1) * 4 + mi;
#pragma unroll
        for (int n = 0; n < 4; ++n)
#pragma unroll
          for (int r2 = 0; r2 < 4; ++r2) {
            int row_loc = mi * 16 + kg * 4 + r2;
            int col_loc = wc * 64 + n * 16 + fr;
            ep[row_loc * 264 + col_loc] = (_Float16)fmaxf(acc[m][n][r2] + bias_n[n], 0.f);
          }
      }
    }
    __syncthreads();
#pragma unroll
    for (int i = 0; i < 4; ++i) {
      int chunk = i * 512 + tid;
      int row = chunk >> 5, c16 = chunk & 31;
      int r = q * 64 + row;
      if (r < cnt)
        *(u16x8*)&hbuf[(size_t)(m0 + r) * HID + n0 + c16 * 8] =
            *(const u16x8*)&ep[row * 264 + c16 * 8];
    }
  }
}

// ---------------- GEMM2: slotbuf[pos] = (h @ P2[e] + b2[e]) * w ----------------
__global__ __launch_bounds__(512, 2) void gemm2_kernel(
    const _Float16* __restrict__ hbuf, const _Float16* __restrict__ P2,
    const float* __restrict__ b2, const int* __restrict__ wsi,
    float* __restrict__ slotbuf) {
  __shared__ _Float16 smem[32768];
  int d = blockIdx.x;
  int orig = (d & 7) * (GRID2B >> 3) + (d >> 3);
  int tile = orig / NNT2;
  int nt = orig % NNT2;
  int cnt = (wsi + 528)[tile];
  if (cnt == 0) return;
  int e = (wsi + 16)[tile];
  int m0 = (wsi + 272)[tile];
  const float* wsorted = (const float*)(wsi + 50176);
  int n0 = nt * 256;
  int tid = threadIdx.x, lane = tid & 63, w = tid >> 6;
  int wr = w >> 2, wc = w & 3;
  int fr = lane & 15, kg = lane >> 4;

  int gm_a = wr * 8 + (w & 3);
  int gm_b = gm_a + 4;
  int ra = gm_a * 16 + fr; ra = ra < cnt ? ra : cnt - 1;
  int rb2 = gm_b * 16 + fr; rb2 = rb2 < cnt ? rb2 : cnt - 1;
  const _Float16* paA = hbuf + (size_t)(m0 + ra) * HID + kg * 8;
  const _Float16* paB = hbuf + (size_t)(m0 + rb2) * HID + kg * 8;
  const _Float16* pbw = P2 + ((size_t)e * NNT2 + nt) * ((size_t)NKS2 * 8192)
                         + (size_t)(wc * 4) * 512 + lane * 8;

  f32x4 acc[8][4];
#pragma unroll
  for (int m = 0; m < 8; ++m)
#pragma unroll
    for (int n = 0; n < 4; ++n) acc[m][n] = (f32x4){0.f, 0.f, 0.f, 0.f};

  GEMM_PIPE(NKS2)

  float bias_n[4];
#pragma unroll
  for (int n = 0; n < 4; ++n) bias_n[n] = b2[e * OUT_DIM + n0 + wc * 64 + n * 16 + fr];

#pragma unroll
  for (int m = 0; m < 8; ++m) {
#pragma unroll
    for (int r2 = 0; r2 < 4; ++r2) {
      int r = wr * 128 + m * 16 + kg * 4 + r2;
      if (r < cnt) {
        float wgt = wsorted[m0 + r];
        float* orow = slotbuf + (size_t)(m0 + r) * OUT_DIM + n0;
#pragma unroll
        for (int n = 0; n < 4; ++n)
          orow[wc * 64 + n * 16 + fr] = (acc[m][n][r2] + bias_n[n]) * wgt;
      }
    }
  }
}

// ---------------- combine ----------------
__global__ __launch_bounds__(256) void combine_kernel(
    const float* __restrict__ slotbuf, const int* __restrict__ wsi,
    float* __restrict__ out) {
  int idx = blockIdx.x * 256 + threadIdx.x;
  int b = idx >> 9, c4 = (idx & 511) * 4;
  const int* inv = wsi + INV_OFF;
  int p0 = inv[b * 2], p1 = inv[b * 2 + 1];
  float4 a = *(const float4*)&slotbuf[(size_t)p0 * OUT_DIM + c4];
  float4 c = *(const float4*)&slotbuf[(size_t)p1 * OUT_DIM + c4];
  float4 o; o.x = a.x + c.x; o.y = a.y + c.y; o.z = a.z + c.z; o.w = a.w + c.w;
  *(float4*)&out[(size_t)b * OUT_DIM + c4] = o;
}

// ================= fallback path (round-1 proven kernels, 128-row tiles) =================
#define FB_MAX_TILES 136
__global__ void schedule_fb(int* __restrict__ wsi) {
  if (threadIdx.x != 0 || blockIdx.x != 0) return;
  int* counts = wsi; int* cursor = wsi + 8;
  int* te = wsi + 16; int* tm = wsi + 272; int* tc = wsi + 528;
  int off = 0, t = 0;
  for (int e = 0; e < NE; ++e) {
    int c = counts[e];
    cursor[e] = off;
    int nt = (c + 127) >> 7;
    for (int i = 0; i < nt; ++i) {
      te[t] = e; tm[t] = off + i * 128;
      int rem = c - i * 128;
      tc[t] = rem < 128 ? rem : 128;
      ++t;
    }
    off += c;
  }
  for (; t < FB_MAX_TILES; ++t) { te[t] = 0; tm[t] = 0; tc[t] = 0; }
}

__global__ __launch_bounds__(256, 2) void gemm1_fb(
    const float* __restrict__ id_emb, const float* __restrict__ llm_emb,
    const float* __restrict__ W1, const float* __restrict__ b1,
    const int* __restrict__ wsi, _Float16* __restrict__ h) {
  const int* te = wsi + 16; const int* tm = wsi + 272; const int* tc = wsi + 528;
  const int* rows = wsi + 33792;
  int tile = blockIdx.x;
  int cnt = tc[tile];
  if (cnt == 0) return;
  int e = te[tile], m0 = tm[tile];
  int n0 = blockIdx.y * 128;
  const float* Wb = W1 + (size_t)e * IN_DIM * HID;
  __shared__ _Float16 As[128][40];
  __shared__ _Float16 Bs[128][40];
  int tid = threadIdx.x;
  int lane = tid & 63, w = tid >> 6;
  int wr = w >> 1, wc = w & 1;
  int fr = lane & 15, kg = lane >> 4;
  f32x4 acc[4][4];
#pragma unroll
  for (int m = 0; m < 4; ++m)
#pragma unroll
    for (int n = 0; n < 4; ++n) acc[m][n] = (f32x4){0.f, 0.f, 0.f, 0.f};
  int a_ks = (tid & 3) * 8;
  int a_r = tid >> 2;
  int brow[2];
#pragma unroll
  for (int i = 0; i < 2; ++i) {
    int r = a_r + i * 64;
    brow[i] = (r < cnt) ? (rows[m0 + r] >> 1) : -1;
  }
  int b_c = tid & 127, b_kq = tid >> 7;
  for (int kt = 0; kt < IN_DIM; kt += 32) {
#pragma unroll
    for (int i = 0; i < 2; ++i) {
      int r = a_r + i * 64;
      float v[8];
      if (brow[i] >= 0) {
        int k = kt + a_ks;
        const float* src = (k < ID_DIM)
            ? (id_emb + (size_t)brow[i] * ID_DIM + k)
            : (llm_emb + (size_t)brow[i] * LLM_DIM + (k - ID_DIM));
        float4 v0 = *(const float4*)src;
        float4 v1 = *(const float4*)(src + 4);
        v[0] = v0.x; v[1] = v0.y; v[2] = v0.z; v[3] = v0.w;
        v[4] = v1.x; v[5] = v1.y; v[6] = v1.z; v[7] = v1.w;
      } else {
#pragma unroll
        for (int j = 0; j < 8; ++j) v[j] = 0.f;
      }
      union { u16x8 u; _Float16 f[8]; } cv;
#pragma unroll
      for (int j = 0; j < 8; ++j) cv.f[j] = (_Float16)v[j];
      *reinterpret_cast<u16x8*>(&As[r][a_ks]) = cv.u;
    }
#pragma unroll
    for (int i = 0; i < 2; ++i) {
      int kc = b_kq + i * 2;
      int k0 = kt + kc * 8;
      union { u16x8 u; _Float16 f[8]; } cv;
#pragma unroll
      for (int j = 0; j < 8; ++j)
        cv.f[j] = (_Float16)Wb[(size_t)(k0 + j) * HID + n0 + b_c];
      *reinterpret_cast<u16x8*>(&Bs[b_c][kc * 8]) = cv.u;
    }
    __syncthreads();
    f16x8 af[4], bf[4];
#pragma unroll
    for (int m = 0; m < 4; ++m)
      af[m] = *reinterpret_cast<const f16x8*>(&As[wr * 64 + m * 16 + fr][kg * 8]);
#pragma unroll
    for (int n = 0; n < 4; ++n)
      bf[n] = *reinterpret_cast<const f16x8*>(&Bs[wc * 64 + n * 16 + fr][kg * 8]);
#pragma unroll
    for (int m = 0; m < 4; ++m)
#pragma unroll
      for (int n = 0; n < 4; ++n)
        acc[m][n] = __builtin_amdgcn_mfma_f32_16x16x32_f16(af[m], bf[n], acc[m][n], 0, 0, 0);
    __syncthreads();
  }
#pragma unroll
  for (int m = 0; m < 4; ++m) {
    int rbv = wr * 64 + m * 16 + kg * 4;
#pragma unroll
    for (int n = 0; n < 4; ++n) {
      int col = n0 + wc * 64 + n * 16 + fr;
      float bias = b1[e * HID + col];
#pragma unroll
      for (int r2 = 0; r2 < 4; ++r2) {
        int r = rbv + r2;
        if (r < cnt) {
          float v = fmaxf(acc[m][n][r2] + bias, 0.f);
          h[(size_t)(m0 + r) * HID + col] = (_Float16)v;
        }
      }
    }
  }
}

__global__ __launch_bounds__(256, 2) void gemm2_fb(
    const _Float16* __restrict__ h, const float* __restrict__ W2,
    const float* __restrict__ b2, const int* __restrict__ wsi,
    float* __restrict__ out) {
  const int* te = wsi + 16; const int* tm = wsi + 272; const int* tc = wsi + 528;
  const int* rows = wsi + 33792;
  const float* wsorted = (const float*)(wsi + 50176);
  int tile = blockIdx.x;
  int cnt = tc[tile];
  if (cnt == 0) return;
  int e = te[tile], m0 = tm[tile];
  int n0 = blockIdx.y * 128;
  const float* Wb = W2 + (size_t)e * HID * OUT_DIM;
  __shared__ _Float16 As[128][40];
  __shared__ _Float16 Bs[128][40];
  int tid = threadIdx.x;
  int lane = tid & 63, w = tid >> 6;
  int wr = w >> 1, wc = w & 1;
  int fr = lane & 15, kg = lane >> 4;
  f32x4 acc[4][4];
#pragma unroll
  for (int m = 0; m < 4; ++m)
#pragma unroll
    for (int n = 0; n < 4; ++n) acc[m][n] = (f32x4){0.f, 0.f, 0.f, 0.f};
  int a_ks = (tid & 3) * 8;
  int a_r = tid >> 2;
  int b_c = tid & 127, b_kq = tid >> 7;
  for (int kt = 0; kt < HID; kt += 32) {
#pragma unroll
    for (int i = 0; i < 2; ++i) {
      int r = a_r + i * 64;
      u16x8 v;
      if (r < cnt) {
        v = *reinterpret_cast<const u16x8*>(&h[(size_t)(m0 + r) * HID + kt + a_ks]);
      } else {
        v = (u16x8){0, 0, 0, 0, 0, 0, 0, 0};
      }
      *reinterpret_cast<u16x8*>(&As[r][a_ks]) = v;
    }
#pragma unroll
    for (int i = 0; i < 2; ++i) {
      int kc = b_kq + i * 2;
      int k0 = kt + kc * 8;
      union { u16x8 u; _Float16 f[8]; } cv;
#pragma unroll
      for (int j = 0; j < 8; ++j)
        cv.f[j] = (_Float16)Wb[(size_t)(k0 + j) * OUT_DIM + n0 + b_c];
      *reinterpret_cast<u16x8*>(&Bs[b_c][kc * 8]) = cv.u;
    }
    __syncthreads();
    f16x8 af[4], bf[4];
#pragma unroll
    for (int m = 0; m < 4; ++m)
      af[m] = *reinterpret_cast<const f16x8*>(&As[wr * 64 + m * 16 + fr][kg * 8]);
#pragma unroll
    for (int n = 0; n < 4; ++n)
      bf[n] = *reinterpret_cast<const f16x8*>(&Bs[wc * 64 + n * 16 + fr][kg * 8]);
#pragma unroll
    for (int m = 0; m < 4; ++m)
#pragma unroll
      for (int n = 0; n < 4; ++n)
        acc[m][n] = __builtin_amdgcn_mfma_f32_16x16x32_f16(af[m], bf[n], acc[m][n], 0, 0, 0);
    __syncthreads();
  }
#pragma unroll
  for (int m = 0; m < 4; ++m) {
    int rbv = wr * 64 + m * 16 + kg * 4;
#pragma unroll
    for (int n = 0; n < 4; ++n) {
      int col = n0 + wc * 64 + n * 16 + fr;
      float bias = b2[e * OUT_DIM + col];
#pragma unroll
      for (int r2 = 0; r2 < 4; ++r2) {
        int r = rbv + r2;
        if (r < cnt) {
          int slot = rows[m0 + r];
          int btok = slot >> 1;
          float wgt = wsorted[m0 + r];
          atomicAdd(&out[(size_t)btok * OUT_DIM + col], (acc[m][n][r2] + bias) * wgt);
        }
      }
    }
  }
}

extern "C" void kernel_launch(void* const* d_in, const int* in_sizes, int n_in,
                              void* d_out, int out_size, void* d_ws, size_t ws_size,
                              hipStream_t stream) {
  const float* id_emb  = (const float*)d_in[0];
  const float* llm_emb = (const float*)d_in[1];
  const float* W1  = (const float*)d_in[2];
  const float* b1  = (const float*)d_in[3];
  const float* W2  = (const float*)d_in[4];
  const float* b2  = (const float*)d_in[5];
  const float* gW1 = (const float*)d_in[6];
  const float* gb1 = (const float*)d_in[7];
  const float* gW2 = (const float*)d_in[8];
  const float* gb2 = (const float*)d_in[9];
  float* out = (float*)d_out;
  int* wsi = (int*)d_ws;
  _Float16* h = (_Float16*)((char*)d_ws + OFF_H);
  bool fast = ws_size >= REQ_WS;

  hipMemsetAsync(d_ws, 0, 4096, stream);

  if (fast) {
    _Float16* xf = (_Float16*)((char*)d_ws + OFF_X);
    _Float16* p1 = (_Float16*)((char*)d_ws + OFF_P1);
    _Float16* p2 = (_Float16*)((char*)d_ws + OFF_P2);
    float* slotbuf = (float*)((char*)d_ws + OFF_SLOT);
    gate_kernel<<<B_TOK / 4, 256, 0, stream>>>(id_emb, llm_emb, gW1, gb1, gW2, gb2, wsi, xf);
    schedule_kernel<<<1, 64, 0, stream>>>(wsi);
    scatter_kernel<<<NSLOT / 256, 256, 0, stream>>>(wsi);
    pack_w<<<dim3(NKS1, NNT1, NE), 256, 0, stream>>>(W1, p1, HID, NNT1, NKS1);
    pack_w<<<dim3(NKS2, NNT2, NE), 256, 0, stream>>>(W2, p2, OUT_DIM, NNT2, NKS2);
    gemm1_kernel<<<GRID1B, 512, 0, stream>>>(xf, p1, b1, wsi, h);
    gemm2_kernel<<<GRID2B, 512, 0, stream>>>(h, p2, b2, wsi, slotbuf);
    combine_kernel<<<(B_TOK * OUT_DIM / 4) / 256, 256, 0, stream>>>(slotbuf, wsi, out);
  } else {
    hipMemsetAsync(d_out, 0, (size_t)B_TOK * OUT_DIM * sizeof(float), stream);
    gate_kernel<<<B_TOK / 4, 256, 0, stream>>>(id_emb, llm_emb, gW1, gb1, gW2, gb2, wsi, nullptr);
    schedule_fb<<<1, 64, 0, stream>>>(wsi);
    scatter_kernel<<<NSLOT / 256, 256, 0, stream>>>(wsi);
    gemm1_fb<<<dim3(FB_MAX_TILES, 32), 256, 0, stream>>>(id_emb, llm_emb, W1, b1, wsi, h);
    gemm2_fb<<<dim3(FB_MAX_TILES, 16), 256, 0, stream>>>(h, W2, b2, wsi, out);
  }
}

// Round 14
// 1851.688 us; speedup vs baseline: 1.2244x; 1.2244x over previous
//
#include <hip/hip_runtime.h>
#include <hip/hip_bf16.h>
#include <hip/hip_fp16.h>

#define B_TOK 8192
#define ID_DIM 1024
#define LLM_DIM 4096
#define IN_DIM 5120
#define OUT_DIM 2048
#define HID 4096
#define NE 8
#define GH 16
#define NSLOT (2 * B_TOK)

// 256^2 geometry, K-step = 32, quad-buffered (3 K-steps in flight)
#define NNT1 16      // HID/256
#define NKS1 160     // IN_DIM/32
#define NNT2 8       // OUT_DIM/256
#define NKS2 128     // HID/32
#define MT256 72
#define GRID1B (MT256 * NNT1)   // 1152, %8==0
#define GRID2B (MT256 * NNT2)   // 576,  %8==0

typedef _Float16 f16x8 __attribute__((ext_vector_type(8)));
typedef float f32x4 __attribute__((ext_vector_type(4)));
typedef unsigned short u16;
typedef u16 u16x8 __attribute__((ext_vector_type(8)));

// ---- workspace byte offsets ----
#define OFF_H   (1ull << 20)
#define OFF_X   (OFF_H + (size_t)NSLOT * HID * 2)       // h: 134 MB
#define OFF_P1  (OFF_X + (size_t)B_TOK * IN_DIM * 2)    // Xf16: 84 MB
#define OFF_P2  (OFF_P1 + (size_t)NE * NNT1 * NKS1 * 16384) // packed W1: 335 MB
#define REQ_WS  (OFF_P2 + (size_t)NE * NNT2 * NKS2 * 16384) // packed W2: 134 MB
#define OFF_SLOT OFF_P1   // gemm2 per-slot output aliases dead P1

#define INV_OFF 66560

__device__ __forceinline__ void gll16(void* lds, const void* gsrc) {
  __builtin_amdgcn_global_load_lds(
      (const __attribute__((address_space(1))) unsigned int*)gsrc,
      (__attribute__((address_space(3))) unsigned int*)lds, 16, 0, 0);
}

// ---------------- gate ----------------
__global__ __launch_bounds__(256) void gate_kernel(
    const float* __restrict__ id_emb, const float* __restrict__ llm_emb,
    const float* __restrict__ gW1, const float* __restrict__ gb1,
    const float* __restrict__ gW2, const float* __restrict__ gb2,
    int* __restrict__ wsi, _Float16* __restrict__ xf16) {
  int wave = (blockIdx.x * blockDim.x + threadIdx.x) >> 6;
  int lane = threadIdx.x & 63;
  if (wave >= B_TOK) return;
  int b = wave;
  float acc[GH];
#pragma unroll
  for (int j = 0; j < GH; ++j) acc[j] = 0.f;
  for (int k = lane; k < IN_DIM; k += 64) {
    float x = (k < ID_DIM) ? id_emb[(size_t)b * ID_DIM + k]
                           : llm_emb[(size_t)b * LLM_DIM + (k - ID_DIM)];
    if (xf16) xf16[(size_t)b * IN_DIM + k] = (_Float16)x;
    const float* grow = gW1 + (size_t)k * GH;
#pragma unroll
    for (int j = 0; j < GH; ++j) acc[j] += x * grow[j];
  }
#pragma unroll
  for (int j = 0; j < GH; ++j) {
    for (int off = 32; off > 0; off >>= 1) acc[j] += __shfl_xor(acc[j], off);
  }
  if (lane == 0) {
    float logits[NE];
#pragma unroll
    for (int e = 0; e < NE; ++e) logits[e] = gb2[e];
#pragma unroll
    for (int j = 0; j < GH; ++j) {
      float hg = fmaxf(acc[j] + gb1[j], 0.f);
#pragma unroll
      for (int e = 0; e < NE; ++e) logits[e] += hg * gW2[j * NE + e];
    }
    int i0 = 0; float v0 = logits[0];
#pragma unroll
    for (int e = 1; e < NE; ++e) if (logits[e] > v0) { v0 = logits[e]; i0 = e; }
    int i1 = -1; float v1 = -1e30f;
#pragma unroll
    for (int e = 0; e < NE; ++e) if (e != i0 && logits[e] > v1) { v1 = logits[e]; i1 = e; }
    float ex = expf(v1 - v0);
    float w0 = 1.f / (1.f + ex);
    float w1 = ex / (1.f + ex);
    int* eidx = wsi + 1024;
    float* wsl = (float*)(wsi + 17408);
    eidx[b * 2] = i0; eidx[b * 2 + 1] = i1;
    wsl[b * 2] = w0; wsl[b * 2 + 1] = w1;
    atomicAdd(&wsi[i0], 1);
    atomicAdd(&wsi[i1], 1);
  }
}

// ---------------- schedule: 256-row tiles ----------------
__global__ void schedule_kernel(int* __restrict__ wsi) {
  if (threadIdx.x != 0 || blockIdx.x != 0) return;
  int* counts = wsi; int* cursor = wsi + 8;
  int* te = wsi + 16; int* tm = wsi + 272; int* tc = wsi + 528;
  int off = 0, t = 0;
  for (int e = 0; e < NE; ++e) {
    int c = counts[e];
    cursor[e] = off;
    int nt = (c + 255) >> 8;
    for (int i = 0; i < nt; ++i) {
      te[t] = e; tm[t] = off + i * 256;
      int rem = c - i * 256;
      tc[t] = rem < 256 ? rem : 256;
      ++t;
    }
    off += c;
  }
  for (; t < MT256; ++t) { te[t] = 0; tm[t] = 0; tc[t] = 0; }
}

// ---------------- scatter (+ inverse map) ----------------
__global__ __launch_bounds__(256) void scatter_kernel(int* __restrict__ wsi) {
  int s = blockIdx.x * blockDim.x + threadIdx.x;
  if (s >= NSLOT) return;
  int* cursor = wsi + 8;
  const int* eidx = wsi + 1024;
  const float* wsl = (const float*)(wsi + 17408);
  int* rows = wsi + 33792;
  float* wsorted = (float*)(wsi + 50176);
  int* inv = wsi + INV_OFF;
  int e = eidx[s];
  int pos = atomicAdd(&cursor[e], 1);
  rows[pos] = s;
  wsorted[pos] = wsl[s];
  inv[s] = pos;
}

// ---------------- pack weights: coalesced read -> LDS -> packed blocks ----------------
// P block 8192 f16 per (e,nt,ks):
//   dst[gn*512 + l*8 + j] = W[k = ks*32 + (l>>4)*8 + j][col = nt*256 + gn*16 + (l&15)]
__global__ __launch_bounds__(256) void pack_w(
    const float* __restrict__ W, _Float16* __restrict__ P,
    int N, int NNT, int NKS) {
  __shared__ _Float16 lds[32 * 264];  // 32 rows x 256 cols, stride 264 (bank spread)
  int ks = blockIdx.x, nt = blockIdx.y, e = blockIdx.z;
  const float* src = W + ((size_t)e * NKS * 32 + (size_t)ks * 32) * N + nt * 256;
  _Float16* dst = P + (((size_t)e * NNT + nt) * NKS + ks) * 8192;
  int t = threadIdx.x;
  // phase A: coalesced float4 row reads, convert fp32->f16, row-major into LDS
  int r = t >> 3, c0 = (t & 7) * 32;
  const float* srow = src + (size_t)r * N + c0;
#pragma unroll
  for (int i = 0; i < 4; ++i) {
    float4 v0 = *(const float4*)(srow + i * 8);
    float4 v1 = *(const float4*)(srow + i * 8 + 4);
    union { u16x8 u; _Float16 f[8]; } cv;
    cv.f[0] = (_Float16)v0.x; cv.f[1] = (_Float16)v0.y;
    cv.f[2] = (_Float16)v0.z; cv.f[3] = (_Float16)v0.w;
    cv.f[4] = (_Float16)v1.x; cv.f[5] = (_Float16)v1.y;
    cv.f[6] = (_Float16)v1.z; cv.f[7] = (_Float16)v1.w;
    *(u16x8*)&lds[r * 264 + c0 + i * 8] = cv.u;
  }
  __syncthreads();
  // phase B: permuted gather from LDS -> coalesced 16B packed writes
  int l = t & 63, q = t >> 6;
  int fr = l & 15, kg = l >> 4;
#pragma unroll
  for (int gi = 0; gi < 4; ++gi) {
    int gn = q * 4 + gi;
    union { u16x8 u; _Float16 f[8]; } cv;
#pragma unroll
    for (int j = 0; j < 8; ++j)
      cv.f[j] = lds[(kg * 8 + j) * 264 + gn * 16 + fr];
    *(u16x8*)(dst + gn * 512 + l * 8) = cv.u;
  }
}

// ======================= reg-pipelined deep GEMM (round-7 proven optimum) =======================
#define SBAR __builtin_amdgcn_s_barrier()
#define SCHB __builtin_amdgcn_sched_barrier(0)
#define VMW(n) asm volatile("s_waitcnt vmcnt(" #n ")" ::: "memory")

// stage helpers: LDS dst wave-uniform (HW adds lane*16B); global src per-lane
#define ST_A(Aw, ks_, pa_, gm_) gll16((Aw) + (gm_) * 512, (pa_) + (size_t)(ks_) * 32)
#define ST_B(Bw, ks_, gn_) \
  gll16((Bw) + (gn_) * 512, pb + (size_t)(ks_) * 8192 + (gn_) * 512)

#define STAGE4(kt)                                                   \
  { _Float16* Aw = smem + ((kt) & 3) * 8192;                         \
    _Float16* Bw = smem + 32768 + ((kt) & 3) * 8192;                 \
    ST_A(Aw, kt, paA, gm_a); ST_A(Aw, kt, paB, gm_b);                \
    ST_B(Bw, kt, gnA); ST_B(Bw, kt, gnB); }

#define READ_A0B(A0s, Bs, Acp, Bcp)                                   \
  _Pragma("unroll") for (int m = 0; m < 4; ++m)                       \
      A0s[m] = *(const f16x8*)((Acp) + (wr * 8 + m) * 512 + lane * 8);\
  _Pragma("unroll") for (int n = 0; n < 4; ++n)                       \
      Bs[n] = *(const f16x8*)((Bcp) + (wc * 4 + n) * 512 + lane * 8);

#define READ_A1(Acp)                                                  \
  _Pragma("unroll") for (int m = 0; m < 4; ++m)                       \
      A1[m] = *(const f16x8*)((Acp) + (wr * 8 + 4 + m) * 512 + lane * 8);

#define MFMA_CL(As, Bs, MO)                                           \
  __builtin_amdgcn_s_setprio(1);                                      \
  _Pragma("unroll") for (int m = 0; m < 4; ++m)                       \
      _Pragma("unroll") for (int n = 0; n < 4; ++n)                   \
          acc[(MO) + m][n] = __builtin_amdgcn_mfma_f32_16x16x32_f16(  \
              As[m], Bs[n], acc[(MO) + m][n], 0, 0, 0);               \
  __builtin_amdgcn_s_setprio(0);

// per-iter: regs A0c/Bc hold frags(k); 1 barrier; reads overlap MFMA via
// counted lgkmcnt (compiler-inserted) instead of lgkmcnt(0) drains.
#define PIPE_ITER(A0c, Bc_, A0n, Bn_, k, NKS)                         \
  { if ((k) < (NKS) - 2) { VMW(4); } else { VMW(0); }                 \
    SCHB; SBAR;                                                       \
    if ((k) + 3 < (NKS)) STAGE4((k) + 3);                             \
    _Float16* Acur = smem + ((k) & 3) * 8192;                         \
    READ_A1(Acur); SCHB;                                              \
    MFMA_CL(A0c, Bc_, 0)                                              \
    if ((k) + 1 < (NKS)) {                                            \
      _Float16* An_ = smem + (((k) + 1) & 3) * 8192;                  \
      _Float16* Bn2 = smem + 32768 + (((k) + 1) & 3) * 8192;          \
      READ_A0B(A0n, Bn_, An_, Bn2)                                    \
    }                                                                 \
    SCHB;                                                             \
    MFMA_CL(A1, Bc_, 4) }

#define GEMM_PIPE(NKS)                                                \
  f16x8 A0x[4], Bx[4], A0y[4], By[4], A1[4];                          \
  STAGE4(0) STAGE4(1) STAGE4(2)                                       \
  VMW(8); SCHB; SBAR;                                                 \
  READ_A0B(A0x, Bx, smem, smem + 32768)                               \
  for (int k = 0; k < (NKS); k += 2) {                                \
    PIPE_ITER(A0x, Bx, A0y, By, k, (NKS))                             \
    PIPE_ITER(A0y, By, A0x, Bx, (k + 1), (NKS))                       \
  }

// ---------------- GEMM1: h = relu(gather(Xf16) @ P1[e] + b1[e]) ----------------
__global__ __launch_bounds__(512, 2) void gemm1_kernel(
    const _Float16* __restrict__ Xf, const _Float16* __restrict__ P1,
    const float* __restrict__ b1, const int* __restrict__ wsi,
    _Float16* __restrict__ hbuf) {
  __shared__ _Float16 smem[65536];  // 128KB: A quad 4x16KB, B quad 4x16KB
  int d = blockIdx.x;
  int orig = (d & 7) * (GRID1B >> 3) + (d >> 3);
  int tile = orig / NNT1;   // tile-major: XCD chunk shares A m-tiles
  int nt = orig % NNT1;
  int cnt = (wsi + 528)[tile];
  if (cnt == 0) return;
  int e = (wsi + 16)[tile];
  int m0 = (wsi + 272)[tile];
  const int* rows = wsi + 33792;
  int n0 = nt * 256;
  int tid = threadIdx.x, lane = tid & 63, w = tid >> 6;
  int wr = w >> 2, wc = w & 3;
  int fr = lane & 15, kg = lane >> 4;

  int gm_a = wr * 8 + (w & 3);
  int gm_b = gm_a + 4;
  int gnA = w * 2, gnB = w * 2 + 1;
  int ra = gm_a * 16 + fr; ra = ra < cnt ? ra : cnt - 1;
  int rb2 = gm_b * 16 + fr; rb2 = rb2 < cnt ? rb2 : cnt - 1;
  const _Float16* paA = Xf + (size_t)(rows[m0 + ra] >> 1) * IN_DIM + kg * 8;
  const _Float16* paB = Xf + (size_t)(rows[m0 + rb2] >> 1) * IN_DIM + kg * 8;
  const _Float16* pb = P1 + ((size_t)e * NNT1 + nt) * ((size_t)NKS1 * 8192) + lane * 8;

  f32x4 acc[8][4];
#pragma unroll
  for (int m = 0; m < 8; ++m)
#pragma unroll
    for (int n = 0; n < 4; ++n) acc[m][n] = (f32x4){0.f, 0.f, 0.f, 0.f};

  GEMM_PIPE(NKS1)

  float bias_n[4];
#pragma unroll
  for (int n = 0; n < 4; ++n) bias_n[n] = b1[e * HID + n0 + wc * 64 + n * 16 + fr];

  // epilogue: relu -> LDS transpose (per wr-half) -> coalesced 16B h writes
  _Float16* ep = smem;  // [128][264]
#pragma unroll
  for (int hh = 0; hh < 2; ++hh) {
    __syncthreads();
    if (wr == hh) {
#pragma unroll
      for (int m = 0; m < 8; ++m)
#pragma unroll
        for (int n = 0; n < 4; ++n)
#pragma unroll
          for (int r2 = 0; r2 < 4; ++r2) {
            int row_loc = m * 16 + kg * 4 + r2;
            int col_loc = wc * 64 + n * 16 + fr;
            ep[row_loc * 264 + col_loc] = (_Float16)fmaxf(acc[m][n][r2] + bias_n[n], 0.f);
          }
    }
    __syncthreads();
#pragma unroll
    for (int i = 0; i < 8; ++i) {
      int chunk = i * 512 + tid;
      int row = chunk >> 5, c16 = chunk & 31;
      int r = hh * 128 + row;
      if (r < cnt)
        *(u16x8*)&hbuf[(size_t)(m0 + r) * HID + n0 + c16 * 8] =
            *(const u16x8*)&ep[row * 264 + c16 * 8];
    }
  }
}

// ---------------- GEMM2: slotbuf[pos] = (h @ P2[e] + b2[e]) * w ----------------
__global__ __launch_bounds__(512, 2) void gemm2_kernel(
    const _Float16* __restrict__ hbuf, const _Float16* __restrict__ P2,
    const float* __restrict__ b2, const int* __restrict__ wsi,
    float* __restrict__ slotbuf) {
  __shared__ _Float16 smem[65536];
  int d = blockIdx.x;
  int orig = (d & 7) * (GRID2B >> 3) + (d >> 3);
  int tile = orig / NNT2;
  int nt = orig % NNT2;
  int cnt = (wsi + 528)[tile];
  if (cnt == 0) return;
  int e = (wsi + 16)[tile];
  int m0 = (wsi + 272)[tile];
  const float* wsorted = (const float*)(wsi + 50176);
  int n0 = nt * 256;
  int tid = threadIdx.x, lane = tid & 63, w = tid >> 6;
  int wr = w >> 2, wc = w & 3;
  int fr = lane & 15, kg = lane >> 4;

  int gm_a = wr * 8 + (w & 3);
  int gm_b = gm_a + 4;
  int gnA = w * 2, gnB = w * 2 + 1;
  int ra = gm_a * 16 + fr; ra = ra < cnt ? ra : cnt - 1;
  int rb2 = gm_b * 16 + fr; rb2 = rb2 < cnt ? rb2 : cnt - 1;
  const _Float16* paA = hbuf + (size_t)(m0 + ra) * HID + kg * 8;
  const _Float16* paB = hbuf + (size_t)(m0 + rb2) * HID + kg * 8;
  const _Float16* pb = P2 + ((size_t)e * NNT2 + nt) * ((size_t)NKS2 * 8192) + lane * 8;

  f32x4 acc[8][4];
#pragma unroll
  for (int m = 0; m < 8; ++m)
#pragma unroll
    for (int n = 0; n < 4; ++n) acc[m][n] = (f32x4){0.f, 0.f, 0.f, 0.f};

  GEMM_PIPE(NKS2)

  float bias_n[4];
#pragma unroll
  for (int n = 0; n < 4; ++n) bias_n[n] = b2[e * OUT_DIM + n0 + wc * 64 + n * 16 + fr];

#pragma unroll
  for (int m = 0; m < 8; ++m) {
#pragma unroll
    for (int r2 = 0; r2 < 4; ++r2) {
      int r = wr * 128 + m * 16 + kg * 4 + r2;
      if (r < cnt) {
        float wgt = wsorted[m0 + r];
        float* orow = slotbuf + (size_t)(m0 + r) * OUT_DIM + n0;
#pragma unroll
        for (int n = 0; n < 4; ++n)
          orow[wc * 64 + n * 16 + fr] = (acc[m][n][r2] + bias_n[n]) * wgt;
      }
    }
  }
}

// ---------------- combine ----------------
__global__ __launch_bounds__(256) void combine_kernel(
    const float* __restrict__ slotbuf, const int* __restrict__ wsi,
    float* __restrict__ out) {
  int idx = blockIdx.x * 256 + threadIdx.x;
  int b = idx >> 9, c4 = (idx & 511) * 4;
  const int* inv = wsi + INV_OFF;
  int p0 = inv[b * 2], p1 = inv[b * 2 + 1];
  float4 a = *(const float4*)&slotbuf[(size_t)p0 * OUT_DIM + c4];
  float4 c = *(const float4*)&slotbuf[(size_t)p1 * OUT_DIM + c4];
  float4 o; o.x = a.x + c.x; o.y = a.y + c.y; o.z = a.z + c.z; o.w = a.w + c.w;
  *(float4*)&out[(size_t)b * OUT_DIM + c4] = o;
}

// ================= fallback path (round-1 proven kernels, 128-row tiles) =================
#define FB_MAX_TILES 136
__global__ void schedule_fb(int* __restrict__ wsi) {
  if (threadIdx.x != 0 || blockIdx.x != 0) return;
  int* counts = wsi; int* cursor = wsi + 8;
  int* te = wsi + 16; int* tm = wsi + 272; int* tc = wsi + 528;
  int off = 0, t = 0;
  for (int e = 0; e < NE; ++e) {
    int c = counts[e];
    cursor[e] = off;
    int nt = (c + 127) >> 7;
    for (int i = 0; i < nt; ++i) {
      te[t] = e; tm[t] = off + i * 128;
      int rem = c - i * 128;
      tc[t] = rem < 128 ? rem : 128;
      ++t;
    }
    off += c;
  }
  for (; t < FB_MAX_TILES; ++t) { te[t] = 0; tm[t] = 0; tc[t] = 0; }
}

__global__ __launch_bounds__(256, 2) void gemm1_fb(
    const float* __restrict__ id_emb, const float* __restrict__ llm_emb,
    const float* __restrict__ W1, const float* __restrict__ b1,
    const int* __restrict__ wsi, _Float16* __restrict__ h) {
  const int* te = wsi + 16; const int* tm = wsi + 272; const int* tc = wsi + 528;
  const int* rows = wsi + 33792;
  int tile = blockIdx.x;
  int cnt = tc[tile];
  if (cnt == 0) return;
  int e = te[tile], m0 = tm[tile];
  int n0 = blockIdx.y * 128;
  const float* Wb = W1 + (size_t)e * IN_DIM * HID;
  __shared__ _Float16 As[128][40];
  __shared__ _Float16 Bs[128][40];
  int tid = threadIdx.x;
  int lane = tid & 63, w = tid >> 6;
  int wr = w >> 1, wc = w & 1;
  int fr = lane & 15, kg = lane >> 4;
  f32x4 acc[4][4];
#pragma unroll
  for (int m = 0; m < 4; ++m)
#pragma unroll
    for (int n = 0; n < 4; ++n) acc[m][n] = (f32x4){0.f, 0.f, 0.f, 0.f};
  int a_ks = (tid & 3) * 8;
  int a_r = tid >> 2;
  int brow[2];
#pragma unroll
  for (int i = 0; i < 2; ++i) {
    int r = a_r + i * 64;
    brow[i] = (r < cnt) ? (rows[m0 + r] >> 1) : -1;
  }
  int b_c = tid & 127, b_kq = tid >> 7;
  for (int kt = 0; kt < IN_DIM; kt += 32) {
#pragma unroll
    for (int i = 0; i < 2; ++i) {
      int r = a_r + i * 64;
      float v[8];
      if (brow[i] >= 0) {
        int k = kt + a_ks;
        const float* src = (k < ID_DIM)
            ? (id_emb + (size_t)brow[i] * ID_DIM + k)
            : (llm_emb + (size_t)brow[i] * LLM_DIM + (k - ID_DIM));
        float4 v0 = *(const float4*)src;
        float4 v1 = *(const float4*)(src + 4);
        v[0] = v0.x; v[1] = v0.y; v[2] = v0.z; v[3] = v0.w;
        v[4] = v1.x; v[5] = v1.y; v[6] = v1.z; v[7] = v1.w;
      } else {
#pragma unroll
        for (int j = 0; j < 8; ++j) v[j] = 0.f;
      }
      union { u16x8 u; _Float16 f[8]; } cv;
#pragma unroll
      for (int j = 0; j < 8; ++j) cv.f[j] = (_Float16)v[j];
      *reinterpret_cast<u16x8*>(&As[r][a_ks]) = cv.u;
    }
#pragma unroll
    for (int i = 0; i < 2; ++i) {
      int kc = b_kq + i * 2;
      int k0 = kt + kc * 8;
      union { u16x8 u; _Float16 f[8]; } cv;
#pragma unroll
      for (int j = 0; j < 8; ++j)
        cv.f[j] = (_Float16)Wb[(size_t)(k0 + j) * HID + n0 + b_c];
      *reinterpret_cast<u16x8*>(&Bs[b_c][kc * 8]) = cv.u;
    }
    __syncthreads();
    f16x8 af[4], bf[4];
#pragma unroll
    for (int m = 0; m < 4; ++m)
      af[m] = *reinterpret_cast<const f16x8*>(&As[wr * 64 + m * 16 + fr][kg * 8]);
#pragma unroll
    for (int n = 0; n < 4; ++n)
      bf[n] = *reinterpret_cast<const f16x8*>(&Bs[wc * 64 + n * 16 + fr][kg * 8]);
#pragma unroll
    for (int m = 0; m < 4; ++m)
#pragma unroll
      for (int n = 0; n < 4; ++n)
        acc[m][n] = __builtin_amdgcn_mfma_f32_16x16x32_f16(af[m], bf[n], acc[m][n], 0, 0, 0);
    __syncthreads();
  }
#pragma unroll
  for (int m = 0; m < 4; ++m) {
    int rbv = wr * 64 + m * 16 + kg * 4;
#pragma unroll
    for (int n = 0; n < 4; ++n) {
      int col = n0 + wc * 64 + n * 16 + fr;
      float bias = b1[e * HID + col];
#pragma unroll
      for (int r2 = 0; r2 < 4; ++r2) {
        int r = rbv + r2;
        if (r < cnt) {
          float v = fmaxf(acc[m][n][r2] + bias, 0.f);
          h[(size_t)(m0 + r) * HID + col] = (_Float16)v;
        }
      }
    }
  }
}

__global__ __launch_bounds__(256, 2) void gemm2_fb(
    const _Float16* __restrict__ h, const float* __restrict__ W2,
    const float* __restrict__ b2, const int* __restrict__ wsi,
    float* __restrict__ out) {
  const int* te = wsi + 16; const int* tm = wsi + 272; const int* tc = wsi + 528;
  const int* rows = wsi + 33792;
  const float* wsorted = (const float*)(wsi + 50176);
  int tile = blockIdx.x;
  int cnt = tc[tile];
  if (cnt == 0) return;
  int e = te[tile], m0 = tm[tile];
  int n0 = blockIdx.y * 128;
  const float* Wb = W2 + (size_t)e * HID * OUT_DIM;
  __shared__ _Float16 As[128][40];
  __shared__ _Float16 Bs[128][40];
  int tid = threadIdx.x;
  int lane = tid & 63, w = tid >> 6;
  int wr = w >> 1, wc = w & 1;
  int fr = lane & 15, kg = lane >> 4;
  f32x4 acc[4][4];
#pragma unroll
  for (int m = 0; m < 4; ++m)
#pragma unroll
    for (int n = 0; n < 4; ++n) acc[m][n] = (f32x4){0.f, 0.f, 0.f, 0.f};
  int a_ks = (tid & 3) * 8;
  int a_r = tid >> 2;
  int b_c = tid & 127, b_kq = tid >> 7;
  for (int kt = 0; kt < HID; kt += 32) {
#pragma unroll
    for (int i = 0; i < 2; ++i) {
      int r = a_r + i * 64;
      u16x8 v;
      if (r < cnt) {
        v = *reinterpret_cast<const u16x8*>(&h[(size_t)(m0 + r) * HID + kt + a_ks]);
      } else {
        v = (u16x8){0, 0, 0, 0, 0, 0, 0, 0};
      }
      *reinterpret_cast<u16x8*>(&As[r][a_ks]) = v;
    }
#pragma unroll
    for (int i = 0; i < 2; ++i) {
      int kc = b_kq + i * 2;
      int k0 = kt + kc * 8;
      union { u16x8 u; _Float16 f[8]; } cv;
#pragma unroll
      for (int j = 0; j < 8; ++j)
        cv.f[j] = (_Float16)Wb[(size_t)(k0 + j) * OUT_DIM + n0 + b_c];
      *reinterpret_cast<u16x8*>(&Bs[b_c][kc * 8]) = cv.u;
    }
    __syncthreads();
    f16x8 af[4], bf[4];
#pragma unroll
    for (int m = 0; m < 4; ++m)
      af[m] = *reinterpret_cast<const f16x8*>(&As[wr * 64 + m * 16 + fr][kg * 8]);
#pragma unroll
    for (int n = 0; n < 4; ++n)
      bf[n] = *reinterpret_cast<const f16x8*>(&Bs[wc * 64 + n * 16 + fr][kg * 8]);
#pragma unroll
    for (int m = 0; m < 4; ++m)
#pragma unroll
      for (int n = 0; n < 4; ++n)
        acc[m][n] = __builtin_amdgcn_mfma_f32_16x16x32_f16(af[m], bf[n], acc[m][n], 0, 0, 0);
    __syncthreads();
  }
#pragma unroll
  for (int m = 0; m < 4; ++m) {
    int rbv = wr * 64 + m * 16 + kg * 4;
#pragma unroll
    for (int n = 0; n < 4; ++n) {
      int col = n0 + wc * 64 + n * 16 + fr;
      float bias = b2[e * OUT_DIM + col];
#pragma unroll
      for (int r2 = 0; r2 < 4; ++r2) {
        int r = rbv + r2;
        if (r < cnt) {
          int slot = rows[m0 + r];
          int btok = slot >> 1;
          float wgt = wsorted[m0 + r];
          atomicAdd(&out[(size_t)btok * OUT_DIM + col], (acc[m][n][r2] + bias) * wgt);
        }
      }
    }
  }
}

extern "C" void kernel_launch(void* const* d_in, const int* in_sizes, int n_in,
                              void* d_out, int out_size, void* d_ws, size_t ws_size,
                              hipStream_t stream) {
  const float* id_emb  = (const float*)d_in[0];
  const float* llm_emb = (const float*)d_in[1];
  const float* W1  = (const float*)d_in[2];
  const float* b1  = (const float*)d_in[3];
  const float* W2  = (const float*)d_in[4];
  const float* b2  = (const float*)d_in[5];
  const float* gW1 = (const float*)d_in[6];
  const float* gb1 = (const float*)d_in[7];
  const float* gW2 = (const float*)d_in[8];
  const float* gb2 = (const float*)d_in[9];
  float* out = (float*)d_out;
  int* wsi = (int*)d_ws;
  _Float16* h = (_Float16*)((char*)d_ws + OFF_H);
  bool fast = ws_size >= REQ_WS;

  hipMemsetAsync(d_ws, 0, 4096, stream);

  if (fast) {
    _Float16* xf = (_Float16*)((char*)d_ws + OFF_X);
    _Float16* p1 = (_Float16*)((char*)d_ws + OFF_P1);
    _Float16* p2 = (_Float16*)((char*)d_ws + OFF_P2);
    float* slotbuf = (float*)((char*)d_ws + OFF_SLOT);
    gate_kernel<<<B_TOK / 4, 256, 0, stream>>>(id_emb, llm_emb, gW1, gb1, gW2, gb2, wsi, xf);
    schedule_kernel<<<1, 64, 0, stream>>>(wsi);
    scatter_kernel<<<NSLOT / 256, 256, 0, stream>>>(wsi);
    pack_w<<<dim3(NKS1, NNT1, NE), 256, 0, stream>>>(W1, p1, HID, NNT1, NKS1);
    pack_w<<<dim3(NKS2, NNT2, NE), 256, 0, stream>>>(W2, p2, OUT_DIM, NNT2, NKS2);
    gemm1_kernel<<<GRID1B, 512, 0, stream>>>(xf, p1, b1, wsi, h);
    gemm2_kernel<<<GRID2B, 512, 0, stream>>>(h, p2, b2, wsi, slotbuf);
    combine_kernel<<<(B_TOK * OUT_DIM / 4) / 256, 256, 0, stream>>>(slotbuf, wsi, out);
  } else {
    hipMemsetAsync(d_out, 0, (size_t)B_TOK * OUT_DIM * sizeof(float), stream);
    gate_kernel<<<B_TOK / 4, 256, 0, stream>>>(id_emb, llm_emb, gW1, gb1, gW2, gb2, wsi, nullptr);
    schedule_fb<<<1, 64, 0, stream>>>(wsi);
    scatter_kernel<<<NSLOT / 256, 256, 0, stream>>>(wsi);
    gemm1_fb<<<dim3(FB_MAX_TILES, 32), 256, 0, stream>>>(id_emb, llm_emb, W1, b1, wsi, h);
    gemm2_fb<<<dim3(FB_MAX_TILES, 16), 256, 0, stream>>>(h, W2, b2, wsi, out);
  }
}